// Round 3
// baseline (264.379 us; speedup 1.0000x reference)
//
#include <hip/hip_runtime.h>

// ---------- types / helpers ----------
typedef __bf16 bf16x8 __attribute__((ext_vector_type(8)));
typedef float f32x4 __attribute__((ext_vector_type(4)));
typedef float f32x16 __attribute__((ext_vector_type(16)));

struct alignas(16) US8 { unsigned short us[8]; };

static __device__ inline unsigned short f2bf(float f) {
  union { float f; unsigned u; } v; v.f = f;
  unsigned r = v.u + 0x7fffu + ((v.u >> 16) & 1u);   // RNE
  return (unsigned short)(r >> 16);
}

static __device__ inline void gload16(const unsigned short* g, unsigned short* l) {
  // direct-to-LDS DMA, 16B/lane; LDS dest = wave-uniform base + lane*16
  __builtin_amdgcn_global_load_lds(
      (const __attribute__((address_space(1))) void*)g,
      (__attribute__((address_space(3))) void*)l, 16, 0, 0);
}

// B=8, N=4096, D=128.  32768 total rows.
#define NSEQ 4096
#define DIM 128
#define ROWS 32768
#define KH 4                      // cross-block key splits in attn (grid 1024 -> 4 blocks/CU)

// log2(e)/sqrt(128): folded into q so S exits QK^T already in log2 domain
#define EXPC (1.4426950408889634f * 0.08838834764831845f)

// ---------- prep: weight transposes to bf16, wide (96 blocks) ----------
__global__ void prep_kernel(const float* __restrict__ Wkv, const float* __restrict__ Wp,
                            unsigned short* __restrict__ wkvT, unsigned short* __restrict__ wpT) {
  const int t = threadIdx.x;
  const int d = (t & 63) * 2;
  if (blockIdx.x < 64) {
    const int col = blockIdx.x * 4 + (t >> 6);
    unsigned short lo = f2bf(Wkv[d * 256 + col]);
    unsigned short hi = f2bf(Wkv[(d + 1) * 256 + col]);
    *reinterpret_cast<unsigned*>(&wkvT[col * 128 + d]) = (unsigned)lo | ((unsigned)hi << 16);
  } else {
    const int col = (blockIdx.x - 64) * 4 + (t >> 6);
    unsigned short lo = f2bf(Wp[d * 128 + col]);
    unsigned short hi = f2bf(Wp[(d + 1) * 128 + col]);
    *reinterpret_cast<unsigned*>(&wpT[col * 128 + d]) = (unsigned)lo | ((unsigned)hi << 16);
  }
}

// ---------- q scale+cast -> blocked layout (no LDS, 8 blocks/CU) ----------
// Blocked q_hat layout per batch: [tile(64 rows)][kc 16][lane 64][8]:
//   element = q_hat[row = tile*64+l][d = kc*8+j].
__global__ __launch_bounds__(256, 8) void qcast_kernel(
    const float* __restrict__ q, unsigned short* __restrict__ qo) {
  int i = (blockIdx.x * 256 + threadIdx.x) * 8;
  const float4* p = reinterpret_cast<const float4*>(q + i);
  float4 a = p[0], b = p[1];
  US8 o;
  o.us[0]=f2bf(a.x*EXPC); o.us[1]=f2bf(a.y*EXPC); o.us[2]=f2bf(a.z*EXPC); o.us[3]=f2bf(a.w*EXPC);
  o.us[4]=f2bf(b.x*EXPC); o.us[5]=f2bf(b.y*EXPC); o.us[6]=f2bf(b.z*EXPC); o.us[7]=f2bf(b.w*EXPC);
  int row = i >> 7, d0 = i & 127;
  int bb = row >> 12, n = row & (NSEQ - 1), tile = n >> 6, l = n & 63, kc = d0 >> 3;
  *reinterpret_cast<US8*>(qo + (size_t)bb * NSEQ * DIM + tile * 8192 + kc * 512 + l * 8) = o;
}

// ---------- kv = x @ Wkv + bkv -> k_bf (row-major), v BLOCKED+PERMUTED ----------
// 64 rows per block (512 GEMM blocks -> 2 blocks/CU).
// Blocked V layout per batch: [tile(64 keys)][chunk 16][lane 64][8] where chunk=(mg,dh):
//   element (chunk, l, j) = V[m' = mg*8+j][d = dh*64+l], m' = key order with bit2<->bit3
//   swapped per 16-block (matches 32x32 MFMA C/D->A reg order in attn's PV).
__global__ __launch_bounds__(256, 2) void kv_kernel(
    const float* __restrict__ x, const unsigned short* __restrict__ wkvT,
    const float* __restrict__ bkv,
    unsigned short* __restrict__ kout, unsigned short* __restrict__ vtout) {
  const int tid = threadIdx.x;
  __shared__ __align__(16) unsigned short WT[256 * 136];   // [col][d] stride 136 (69.6 KB)
  const int wv = tid >> 6, lane = tid & 63, l16 = lane & 15, quad = lane >> 4;
  const int row0 = blockIdx.x * 64;

  for (int p = 0; p < 16; ++p) {            // 4096 US8 chunks, b128 both sides
    int c = p * 256 + tid;
    int col = c >> 4, c16 = c & 15;
    *reinterpret_cast<US8*>(&WT[col * 136 + c16 * 8]) =
        *reinterpret_cast<const US8*>(wkvT + col * 128 + c16 * 8);
  }
  __syncthreads();

  bf16x8 afrag[4];
  const int arow = row0 + wv * 16 + l16;
  for (int s = 0; s < 4; ++s) {
    const float4* xp = reinterpret_cast<const float4*>(x + (size_t)arow * DIM + s * 32 + quad * 8);
    float4 u0 = xp[0], u1 = xp[1];
    US8 af;
    af.us[0]=f2bf(u0.x); af.us[1]=f2bf(u0.y); af.us[2]=f2bf(u0.z); af.us[3]=f2bf(u0.w);
    af.us[4]=f2bf(u1.x); af.us[5]=f2bf(u1.y); af.us[6]=f2bf(u1.z); af.us[7]=f2bf(u1.w);
    afrag[s] = __builtin_bit_cast(bf16x8, af);
  }
  f32x4 acc[16];
  for (int g = 0; g < 16; ++g) acc[g] = f32x4{0.f, 0.f, 0.f, 0.f};
  for (int s = 0; s < 4; ++s)
    for (int g = 0; g < 16; ++g) {
      bf16x8 bfr = *reinterpret_cast<const bf16x8*>(&WT[(g * 16 + l16) * 136 + s * 32 + quad * 8]);
      acc[g] = __builtin_amdgcn_mfma_f32_16x16x32_bf16(afrag[s], bfr, acc[g], 0, 0, 0);
    }

  // k half: direct stores (row-major)
  for (int g = 0; g < 8; ++g) {
    float bias = bkv[g * 16 + l16];
    for (int r = 0; r < 4; ++r) {
      int orow = row0 + wv * 16 + quad * 4 + r;   // C/D: row=quad*4+r, col=l16
      kout[(size_t)orow * DIM + g * 16 + l16] = f2bf(acc[g][r] + bias);
    }
  }
  // v half: transpose through LDS (stride 72), then blocked+permuted b128 global stores
  __syncthreads();
  unsigned short* LDSt = WT;                // [d][n_local 64] stride 72
  for (int g = 0; g < 8; ++g) {
    float bias = bkv[128 + g * 16 + l16];
    for (int r = 0; r < 4; ++r)
      LDSt[(g * 16 + l16) * 72 + wv * 16 + quad * 4 + r] = f2bf(acc[g + 8][r] + bias);
  }
  __syncthreads();
  const int bb = row0 >> 12;
  const int tile = (row0 & (NSEQ - 1)) >> 6;
  unsigned short* vbo = vtout + (size_t)bb * NSEQ * DIM + (size_t)tile * 8192;
  for (int p = 0; p < 4; ++p) {             // 1024 16B units: 16 chunks x 64 lanes
    int c = p * 256 + tid;
    int idx = c >> 6, l = c & 63;
    int mg = idx >> 1, dh = idx & 1, d = dh * 64 + l;
    int nb = (mg >> 1) * 16 + (mg & 1) * 4;   // first 4-run (bit2<->3 swap)
    uint2 lo = *reinterpret_cast<const uint2*>(&LDSt[d * 72 + nb]);
    uint2 hi = *reinterpret_cast<const uint2*>(&LDSt[d * 72 + nb + 8]);
    uint4 o{lo.x, lo.y, hi.x, hi.y};
    *reinterpret_cast<uint4*>(vbo + (size_t)idx * 512 + l * 8) = o;
  }
}

// ---------- flash attention partials (32x32x16 MFMA, register-P, DMA staging) ----------
// grid 1024 = 8 batches (blockIdx&7) x 32 q-tiles (128 rows) x 4 key-splits.
// Block 256 thr = 4 q-waves x 32 rows; ONE 64-key K-hat/V tile in LDS (32 KB -> 4 blocks/CU,
// 16 waves/CU): barrier/DMA stalls of one block are covered by 3 other resident blocks.
// Softmax: raw v_exp_f32 (log2-domain scores), v_perm truncate-pack, l-rowsum on the
// matrix pipe via all-ones-B MFMA.
__global__ __launch_bounds__(256, 4) void attn_kernel(
    const unsigned short* __restrict__ kbuf, const unsigned short* __restrict__ qblk,
    const unsigned short* __restrict__ vblk,
    float* __restrict__ opart, float* __restrict__ lpart) {
  __shared__ __align__(16) unsigned short SH[16384];   // Ksh 8192 | Vsh 8192 (32 KB)
  unsigned short* Ksh = SH;
  unsigned short* Vsh = SH + 8192;
  const int tid = threadIdx.x;
  const int wv = tid >> 6, lane = tid & 63, l32 = lane & 31, h = lane >> 5;
  const int b = blockIdx.x & 7;
  const int t = blockIdx.x >> 3;
  const int q0 = (t & 31) * 128;
  const int kh = t >> 5;                    // 0..3
  const int key0 = kh * (NSEQ / KH);
  const unsigned short* kb = kbuf + (size_t)b * NSEQ * DIM;
  const unsigned short* qb = qblk + (size_t)b * NSEQ * DIM;
  const unsigned short* vb = vblk + (size_t)b * NSEQ * DIM;

  // per-lane staging sources: 8 chunks/wave/tile, advance 8192 us per tile.
  const unsigned short* gsrc[8];
  int lofs[8];
#pragma unroll
  for (int c = 0; c < 8; ++c) {
    const int idx = wv * 8 + c;
    const unsigned short* p = (idx < 16) ? (qb + idx * 512) : (vb + (size_t)(idx - 16) * 512);
    gsrc[c] = p + (size_t)(key0 >> 6) * 8192 + lane * 8;
    lofs[c] = idx * 512;
  }

  // B-operand frags: this wave's 32 q-rows of k. B[k=h*8+j][n=l32]
  bf16x8 kfrag[8];
  for (int ks = 0; ks < 8; ++ks)
    kfrag[ks] = __builtin_bit_cast(bf16x8, *reinterpret_cast<const US8*>(
        kb + (size_t)(q0 + wv * 32 + l32) * DIM + ks * 16 + h * 8));

  // all-ones B operand for the l-rowsum MFMA (bf16 1.0 = 0x3F80)
  US8 one8;
#pragma unroll
  for (int j = 0; j < 8; ++j) one8.us[j] = 0x3F80;
  const bf16x8 vones = __builtin_bit_cast(bf16x8, one8);

  f32x16 Oacc[4];
  for (int dt = 0; dt < 4; ++dt)
    for (int i = 0; i < 16; ++i) Oacc[dt][i] = 0.f;
  f32x16 Lacc;
  for (int i = 0; i < 16; ++i) Lacc[i] = 0.f;

  constexpr int NT = NSEQ / KH / 64;        // 16
  for (int it = 0; it < NT; ++it) {
    __syncthreads();                        // prior iter's LDS reads done before overwrite
#pragma unroll
    for (int c = 0; c < 8; ++c)
      gload16(gsrc[c] + (size_t)it * 8192, &SH[lofs[c]]);
    __syncthreads();                        // drains vmcnt -> staged data visible

    // S^T tiles: D[m 32][n 32] = sum_ks A(K-hat)[m][k] * B(k-rows)[k][n]
    f32x16 S0, S1;
    for (int i = 0; i < 16; ++i) { S0[i] = 0.f; S1[i] = 0.f; }
    __builtin_amdgcn_s_setprio(1);
#pragma unroll
    for (int ks = 0; ks < 8; ++ks) {
      const unsigned short* kc = &Ksh[(ks * 2 + h) * 512];
      bf16x8 a0 = *reinterpret_cast<const bf16x8*>(&kc[l32 * 8]);
      bf16x8 a1 = *reinterpret_cast<const bf16x8*>(&kc[(32 + l32) * 8]);
      S0 = __builtin_amdgcn_mfma_f32_32x32x16_bf16(a0, kfrag[ks], S0, 0, 0, 0);
      S1 = __builtin_amdgcn_mfma_f32_32x32x16_bf16(a1, kfrag[ks], S1, 0, 0, 0);
    }
    __builtin_amdgcn_s_setprio(0);

    // P = exp2(S^T) truncated to bf16, packed in-lane: frag (T,s) = regs s*8..s*8+7.
    bf16x8 pf[2][2];
#pragma unroll
    for (int T = 0; T < 2; ++T) {
      unsigned pk[8];
#pragma unroll
      for (int i2 = 0; i2 < 8; ++i2) {
        float e0 = __builtin_amdgcn_exp2f(T ? S1[i2 * 2] : S0[i2 * 2]);
        float e1 = __builtin_amdgcn_exp2f(T ? S1[i2 * 2 + 1] : S0[i2 * 2 + 1]);
        pk[i2] = __builtin_amdgcn_perm(__builtin_bit_cast(unsigned, e1),
                                       __builtin_bit_cast(unsigned, e0), 0x07060302u);
      }
      pf[T][0] = __builtin_bit_cast(bf16x8, uint4{pk[0], pk[1], pk[2], pk[3]});
      pf[T][1] = __builtin_bit_cast(bf16x8, uint4{pk[4], pk[5], pk[6], pk[7]});
    }

    // O[n][d] += P[n][m] * V[m][d]: A = pf (regs), B = Vsh chunks (mg = 4T+2s+h).
    // Lacc row-sums the SAME truncated-bf16 P via ones-B MFMA (exact consistency with PV).
    __builtin_amdgcn_s_setprio(1);
#pragma unroll
    for (int T = 0; T < 2; ++T)
#pragma unroll
      for (int s = 0; s < 2; ++s) {
        const int mg = 4 * T + 2 * s + h;
#pragma unroll
        for (int dt = 0; dt < 4; ++dt) {
          bf16x8 bv = *reinterpret_cast<const bf16x8*>(
              &Vsh[(mg * 2 + (dt >> 1)) * 512 + ((dt & 1) * 32 + l32) * 8]);
          Oacc[dt] = __builtin_amdgcn_mfma_f32_32x32x16_bf16(pf[T][s], bv, Oacc[dt], 0, 0, 0);
        }
        Lacc = __builtin_amdgcn_mfma_f32_32x32x16_bf16(pf[T][s], vones, Lacc, 0, 0, 0);
      }
    __builtin_amdgcn_s_setprio(0);
  }

  // l from Lacc: D[n][col] = rowsum(P) for every col; lane with l32==n writes.
#pragma unroll
  for (int i = 0; i < 16; ++i) {
    int n = (i & 3) + 8 * (i >> 2) + 4 * h;   // 32x32 C/D row map (measured m74/m101)
    if (l32 == n)
      lpart[(size_t)kh * ROWS + (size_t)b * NSEQ + q0 + wv * 32 + n] = Lacc[i];
  }
  float* ob = opart + (size_t)kh * ROWS * DIM + ((size_t)b * NSEQ + q0 + wv * 32) * DIM;
  for (int dt = 0; dt < 4; ++dt)
    for (int i = 0; i < 16; ++i) {
      int n = (i & 3) + 8 * (i >> 2) + 4 * h;
      ob[n * DIM + dt * 32 + l32] = Oacc[dt][i];
    }
}

// ---------- combine fp32 partials (4 slices), normalize, out = o @ Wp + bp ----------
// 64 rows per block (512 blocks -> 2 blocks/CU).
__global__ __launch_bounds__(256, 2) void combine_proj_kernel(
    const float* __restrict__ opart, const float* __restrict__ lpart,
    const unsigned short* __restrict__ wpT, const float* __restrict__ bp,
    float* __restrict__ out) {
  __shared__ __align__(16) unsigned short WT[128 * 136];
  const int tid = threadIdx.x;
  const int wv = tid >> 6, lane = tid & 63, l16 = lane & 15, quad = lane >> 4;
  const int row0 = blockIdx.x * 64;

  for (int p = 0; p < 8; ++p) {
    int c = p * 256 + tid;
    int col = c >> 4, c16 = c & 15;
    *reinterpret_cast<US8*>(&WT[col * 136 + c16 * 8]) =
        *reinterpret_cast<const US8*>(wpT + col * 128 + c16 * 8);
  }
  __syncthreads();

  f32x4 acc[8];
  for (int g = 0; g < 8; ++g) acc[g] = f32x4{0.f, 0.f, 0.f, 0.f};
  const int arow = row0 + wv * 16 + l16;
  float lsum = 0.f;
#pragma unroll
  for (int p = 0; p < KH; ++p) lsum += lpart[(size_t)p * ROWS + arow];
  float linv = 1.f / lsum;
  for (int s = 0; s < 4; ++s) {
    const size_t base = (size_t)arow * DIM + s * 32 + quad * 8;
    float4 s0{0.f,0.f,0.f,0.f}, s1{0.f,0.f,0.f,0.f};
#pragma unroll
    for (int p = 0; p < KH; ++p) {
      float4 u0 = *reinterpret_cast<const float4*>(opart + (size_t)p * ROWS * DIM + base);
      float4 u1 = *reinterpret_cast<const float4*>(opart + (size_t)p * ROWS * DIM + base + 4);
      s0.x += u0.x; s0.y += u0.y; s0.z += u0.z; s0.w += u0.w;
      s1.x += u1.x; s1.y += u1.y; s1.z += u1.z; s1.w += u1.w;
    }
    US8 af;
    af.us[0]=f2bf(s0.x*linv); af.us[1]=f2bf(s0.y*linv);
    af.us[2]=f2bf(s0.z*linv); af.us[3]=f2bf(s0.w*linv);
    af.us[4]=f2bf(s1.x*linv); af.us[5]=f2bf(s1.y*linv);
    af.us[6]=f2bf(s1.z*linv); af.us[7]=f2bf(s1.w*linv);
    bf16x8 a = __builtin_bit_cast(bf16x8, af);
    for (int g = 0; g < 8; ++g) {
      bf16x8 bfr = *reinterpret_cast<const bf16x8*>(&WT[(g * 16 + l16) * 136 + s * 32 + quad * 8]);
      acc[g] = __builtin_amdgcn_mfma_f32_16x16x32_bf16(a, bfr, acc[g], 0, 0, 0);
    }
  }
  for (int g = 0; g < 8; ++g) {
    float bias = bp[g * 16 + l16];
    for (int r = 0; r < 4; ++r) {
      int orow = row0 + wv * 16 + quad * 4 + r;
      out[(size_t)orow * DIM + g * 16 + l16] = acc[g][r] + bias;
    }
  }
}

extern "C" void kernel_launch(void* const* d_in, const int* in_sizes, int n_in,
                              void* d_out, int out_size, void* d_ws, size_t ws_size,
                              hipStream_t stream) {
  (void)in_sizes; (void)n_in; (void)out_size; (void)ws_size;
  const float* x   = (const float*)d_in[0];
  const float* qg  = (const float*)d_in[1];
  const float* Wkv = (const float*)d_in[2];
  const float* bkv = (const float*)d_in[3];
  const float* Wp  = (const float*)d_in[4];
  const float* bp  = (const float*)d_in[5];
  float* out = (float*)d_out;

  // workspace: 3x bf16 bufs 25.2MB | weights 96KB | l 512KB | O partials (fp32, KH=4) 67MB
  unsigned short* qbf  = (unsigned short*)d_ws;
  unsigned short* kbf  = qbf + (size_t)ROWS * DIM;
  unsigned short* vtbf = kbf + (size_t)ROWS * DIM;
  unsigned short* wkvT = vtbf + (size_t)ROWS * DIM;
  unsigned short* wpT  = wkvT + 256 * 128;
  float* lpart = (float*)(wpT + 128 * 128);
  float* opart = lpart + (size_t)KH * ROWS;

  hipLaunchKernelGGL(prep_kernel, dim3(96), dim3(256), 0, stream, Wkv, Wp, wkvT, wpT);
  hipLaunchKernelGGL(qcast_kernel, dim3(2048), dim3(256), 0, stream, qg, qbf);
  hipLaunchKernelGGL(kv_kernel, dim3(512), dim3(256), 0, stream, x, wkvT, bkv, kbf, vtbf);
  hipLaunchKernelGGL(attn_kernel, dim3(8 * 32 * KH), dim3(256), 0, stream, kbf, qbf, vtbf, opart, lpart);
  hipLaunchKernelGGL(combine_proj_kernel, dim3(ROWS / 64), dim3(256), 0, stream, opart, lpart, wpT, bp, out);
}

// Round 4
// 181.973 us; speedup vs baseline: 1.4528x; 1.4528x over previous
//
#include <hip/hip_runtime.h>

// ---------- types / helpers ----------
typedef __bf16 bf16x8 __attribute__((ext_vector_type(8)));
typedef float f32x4 __attribute__((ext_vector_type(4)));
typedef float f32x16 __attribute__((ext_vector_type(16)));

struct alignas(16) US8 { unsigned short us[8]; };

static __device__ inline unsigned short f2bf(float f) {
  union { float f; unsigned u; } v; v.f = f;
  unsigned r = v.u + 0x7fffu + ((v.u >> 16) & 1u);   // RNE
  return (unsigned short)(r >> 16);
}

static __device__ inline void gload16(const unsigned short* g, unsigned short* l) {
  // direct-to-LDS DMA, 16B/lane; LDS dest = wave-uniform base + lane*16
  __builtin_amdgcn_global_load_lds(
      (const __attribute__((address_space(1))) void*)g,
      (__attribute__((address_space(3))) void*)l, 16, 0, 0);
}

// B=8, N=4096, D=128.  32768 total rows.
#define NSEQ 4096
#define DIM 128
#define ROWS 32768
#define KH 4                      // cross-block key splits in attn (grid 1024)

// log2(e)/sqrt(128): folded into q so S exits QK^T already in log2 domain
#define EXPC (1.4426950408889634f * 0.08838834764831845f)

// ---------- prep: weight transposes to bf16, wide (96 blocks) ----------
__global__ void prep_kernel(const float* __restrict__ Wkv, const float* __restrict__ Wp,
                            unsigned short* __restrict__ wkvT, unsigned short* __restrict__ wpT) {
  const int t = threadIdx.x;
  const int d = (t & 63) * 2;
  if (blockIdx.x < 64) {
    const int col = blockIdx.x * 4 + (t >> 6);
    unsigned short lo = f2bf(Wkv[d * 256 + col]);
    unsigned short hi = f2bf(Wkv[(d + 1) * 256 + col]);
    *reinterpret_cast<unsigned*>(&wkvT[col * 128 + d]) = (unsigned)lo | ((unsigned)hi << 16);
  } else {
    const int col = (blockIdx.x - 64) * 4 + (t >> 6);
    unsigned short lo = f2bf(Wp[d * 128 + col]);
    unsigned short hi = f2bf(Wp[(d + 1) * 128 + col]);
    *reinterpret_cast<unsigned*>(&wpT[col * 128 + d]) = (unsigned)lo | ((unsigned)hi << 16);
  }
}

// ---------- q scale+cast -> blocked layout (no LDS, 8 blocks/CU) ----------
// Blocked q_hat layout per batch: [tile(64 rows)][kc 16][lane 64][8]:
//   element = q_hat[row = tile*64+l][d = kc*8+j].
__global__ __launch_bounds__(256, 8) void qcast_kernel(
    const float* __restrict__ q, unsigned short* __restrict__ qo) {
  int i = (blockIdx.x * 256 + threadIdx.x) * 8;
  const float4* p = reinterpret_cast<const float4*>(q + i);
  float4 a = p[0], b = p[1];
  US8 o;
  o.us[0]=f2bf(a.x*EXPC); o.us[1]=f2bf(a.y*EXPC); o.us[2]=f2bf(a.z*EXPC); o.us[3]=f2bf(a.w*EXPC);
  o.us[4]=f2bf(b.x*EXPC); o.us[5]=f2bf(b.y*EXPC); o.us[6]=f2bf(b.z*EXPC); o.us[7]=f2bf(b.w*EXPC);
  int row = i >> 7, d0 = i & 127;
  int bb = row >> 12, n = row & (NSEQ - 1), tile = n >> 6, l = n & 63, kc = d0 >> 3;
  *reinterpret_cast<US8*>(qo + (size_t)bb * NSEQ * DIM + tile * 8192 + kc * 512 + l * 8) = o;
}

// ---------- kv = x @ Wkv + bkv -> k_bf (row-major), v BLOCKED+PERMUTED ----------
// 64 rows per block (512 GEMM blocks -> 2 blocks/CU).
// Blocked V layout per batch: [tile(64 keys)][chunk 16][lane 64][8] where chunk=(mg,dh):
//   element (chunk, l, j) = V[m' = mg*8+j][d = dh*64+l], m' = key order with bit2<->bit3
//   swapped per 16-block (matches 32x32 MFMA C/D->A reg order in attn's PV).
__global__ __launch_bounds__(256, 2) void kv_kernel(
    const float* __restrict__ x, const unsigned short* __restrict__ wkvT,
    const float* __restrict__ bkv,
    unsigned short* __restrict__ kout, unsigned short* __restrict__ vtout) {
  const int tid = threadIdx.x;
  __shared__ __align__(16) unsigned short WT[256 * 136];   // [col][d] stride 136 (69.6 KB)
  const int wv = tid >> 6, lane = tid & 63, l16 = lane & 15, quad = lane >> 4;
  const int row0 = blockIdx.x * 64;

  for (int p = 0; p < 16; ++p) {            // 4096 US8 chunks, b128 both sides
    int c = p * 256 + tid;
    int col = c >> 4, c16 = c & 15;
    *reinterpret_cast<US8*>(&WT[col * 136 + c16 * 8]) =
        *reinterpret_cast<const US8*>(wkvT + col * 128 + c16 * 8);
  }
  __syncthreads();

  bf16x8 afrag[4];
  const int arow = row0 + wv * 16 + l16;
  for (int s = 0; s < 4; ++s) {
    const float4* xp = reinterpret_cast<const float4*>(x + (size_t)arow * DIM + s * 32 + quad * 8);
    float4 u0 = xp[0], u1 = xp[1];
    US8 af;
    af.us[0]=f2bf(u0.x); af.us[1]=f2bf(u0.y); af.us[2]=f2bf(u0.z); af.us[3]=f2bf(u0.w);
    af.us[4]=f2bf(u1.x); af.us[5]=f2bf(u1.y); af.us[6]=f2bf(u1.z); af.us[7]=f2bf(u1.w);
    afrag[s] = __builtin_bit_cast(bf16x8, af);
  }
  f32x4 acc[16];
  for (int g = 0; g < 16; ++g) acc[g] = f32x4{0.f, 0.f, 0.f, 0.f};
  for (int s = 0; s < 4; ++s)
    for (int g = 0; g < 16; ++g) {
      bf16x8 bfr = *reinterpret_cast<const bf16x8*>(&WT[(g * 16 + l16) * 136 + s * 32 + quad * 8]);
      acc[g] = __builtin_amdgcn_mfma_f32_16x16x32_bf16(afrag[s], bfr, acc[g], 0, 0, 0);
    }

  // k half: direct stores (row-major)
  for (int g = 0; g < 8; ++g) {
    float bias = bkv[g * 16 + l16];
    for (int r = 0; r < 4; ++r) {
      int orow = row0 + wv * 16 + quad * 4 + r;   // C/D: row=quad*4+r, col=l16
      kout[(size_t)orow * DIM + g * 16 + l16] = f2bf(acc[g][r] + bias);
    }
  }
  // v half: transpose through LDS (stride 72), then blocked+permuted b128 global stores
  __syncthreads();
  unsigned short* LDSt = WT;                // [d][n_local 64] stride 72
  for (int g = 0; g < 8; ++g) {
    float bias = bkv[128 + g * 16 + l16];
    for (int r = 0; r < 4; ++r)
      LDSt[(g * 16 + l16) * 72 + wv * 16 + quad * 4 + r] = f2bf(acc[g + 8][r] + bias);
  }
  __syncthreads();
  const int bb = row0 >> 12;
  const int tile = (row0 & (NSEQ - 1)) >> 6;
  unsigned short* vbo = vtout + (size_t)bb * NSEQ * DIM + (size_t)tile * 8192;
  for (int p = 0; p < 4; ++p) {             // 1024 16B units: 16 chunks x 64 lanes
    int c = p * 256 + tid;
    int idx = c >> 6, l = c & 63;
    int mg = idx >> 1, dh = idx & 1, d = dh * 64 + l;
    int nb = (mg >> 1) * 16 + (mg & 1) * 4;   // first 4-run (bit2<->3 swap)
    uint2 lo = *reinterpret_cast<const uint2*>(&LDSt[d * 72 + nb]);
    uint2 hi = *reinterpret_cast<const uint2*>(&LDSt[d * 72 + nb + 8]);
    uint4 o{lo.x, lo.y, hi.x, hi.y};
    *reinterpret_cast<uint4*>(vbo + (size_t)idx * 512 + l * 8) = o;
  }
}

// ---------- flash attention partials (32x32x16 MFMA, register-P, split-stage pipeline) ----------
// grid 1024 = 8 batches x 32 q-tiles (128 rows) x 4 key-splits; 3 blocks/CU
// (__launch_bounds__(256,3): ~170-reg budget, LDS 48 KB -> 144 KB/CU).
// LDS: K-hat single buffer (16 KB) + V double buffer (32 KB). Per iter:
//   [issue V(t+1) -> QK(t) -> SM(t) -> barrier(drain V) -> issue K(t+1) -> PV(t) -> barrier(drain K)]
// V's DMA is covered by QK+SM, K's by PV + the 2 other resident blocks.
// l-rowsum on VALU from pre-truncation exp values (saves 4 MFMA + 16 AGPR vs ones-B MFMA).
__global__ __launch_bounds__(256, 3) void attn_kernel(
    const unsigned short* __restrict__ kbuf, const unsigned short* __restrict__ qblk,
    const unsigned short* __restrict__ vblk,
    float* __restrict__ opart, float* __restrict__ lpart) {
  __shared__ __align__(16) unsigned short SH[24576];   // KB 8192 | VB[2] 16384 (48 KB)
  unsigned short* KB = SH;
  unsigned short* VB = SH + 8192;
  const int tid = threadIdx.x;
  const int wv = tid >> 6, lane = tid & 63, l32 = lane & 31, h = lane >> 5;
  const int b = blockIdx.x & 7;
  const int t = blockIdx.x >> 3;
  const int q0 = (t & 31) * 128;
  const int kh = t >> 5;                    // 0..3
  const int key0 = kh * (NSEQ / KH);
  const unsigned short* kb = kbuf + (size_t)b * NSEQ * DIM;
  // per-wave staging bases: 4 K-chunks (idx = wv*4+c) and 4 V-chunks per tile
  const unsigned short* ksrc = qblk + (size_t)b * NSEQ * DIM + (size_t)(key0 >> 6) * 8192
                               + wv * 4 * 512 + lane * 8;
  const unsigned short* vsrc = vblk + (size_t)b * NSEQ * DIM + (size_t)(key0 >> 6) * 8192
                               + wv * 4 * 512 + lane * 8;
  unsigned short* kdst = KB + wv * 4 * 512;

  constexpr int NT = NSEQ / KH / 64;        // 16

  // prologue: stage K(0), V(0)->VB[0]; kfrag loads overlap the DMA
#pragma unroll
  for (int c = 0; c < 4; ++c) gload16(ksrc + c * 512, kdst + c * 512);
#pragma unroll
  for (int c = 0; c < 4; ++c) gload16(vsrc + c * 512, VB + wv * 4 * 512 + c * 512);

  // B-operand frags: this wave's 32 q-rows of k. B[k=h*8+j][n=l32]
  bf16x8 kfrag[8];
  for (int ks = 0; ks < 8; ++ks)
    kfrag[ks] = __builtin_bit_cast(bf16x8, *reinterpret_cast<const US8*>(
        kb + (size_t)(q0 + wv * 32 + l32) * DIM + ks * 16 + h * 8));

  f32x16 Oacc[4];
  for (int dt = 0; dt < 4; ++dt)
    for (int i = 0; i < 16; ++i) Oacc[dt][i] = 0.f;
  float lsum = 0.f;

  __syncthreads();                          // tile 0 staged (vmcnt(0) + barrier)

  for (int it = 0; it < NT; ++it) {
    // issue V(it+1) DMA into the other V buffer (covered by QK+SM below)
    if (it + 1 < NT) {
      unsigned short* vd = VB + ((it + 1) & 1) * 8192 + wv * 4 * 512;
      const unsigned short* vs = vsrc + (size_t)(it + 1) * 8192;
#pragma unroll
      for (int c = 0; c < 4; ++c) gload16(vs + c * 512, vd + c * 512);
    }

    // S^T tiles: D[m 32][n 32] = sum_ks A(K-hat)[m][k] * B(k-rows)[k][n]
    f32x16 S0, S1;
    for (int i = 0; i < 16; ++i) { S0[i] = 0.f; S1[i] = 0.f; }
    __builtin_amdgcn_s_setprio(1);
#pragma unroll
    for (int ks = 0; ks < 8; ++ks) {
      const unsigned short* kc = &KB[(ks * 2 + h) * 512];
      bf16x8 a0 = *reinterpret_cast<const bf16x8*>(&kc[l32 * 8]);
      bf16x8 a1 = *reinterpret_cast<const bf16x8*>(&kc[(32 + l32) * 8]);
      S0 = __builtin_amdgcn_mfma_f32_32x32x16_bf16(a0, kfrag[ks], S0, 0, 0, 0);
      S1 = __builtin_amdgcn_mfma_f32_32x32x16_bf16(a1, kfrag[ks], S1, 0, 0, 0);
    }
    __builtin_amdgcn_s_setprio(0);

    // P = exp2(S^T) truncated to bf16, packed in-lane; lsum on VALU (pre-truncation).
    bf16x8 pf[2][2];
#pragma unroll
    for (int T = 0; T < 2; ++T) {
      unsigned pk[8];
#pragma unroll
      for (int i2 = 0; i2 < 8; ++i2) {
        float e0 = __builtin_amdgcn_exp2f(T ? S1[i2 * 2] : S0[i2 * 2]);
        float e1 = __builtin_amdgcn_exp2f(T ? S1[i2 * 2 + 1] : S0[i2 * 2 + 1]);
        lsum += e0;
        lsum += e1;
        pk[i2] = __builtin_amdgcn_perm(__builtin_bit_cast(unsigned, e1),
                                       __builtin_bit_cast(unsigned, e0), 0x07060302u);
      }
      pf[T][0] = __builtin_bit_cast(bf16x8, uint4{pk[0], pk[1], pk[2], pk[3]});
      pf[T][1] = __builtin_bit_cast(bf16x8, uint4{pk[4], pk[5], pk[6], pk[7]});
    }

    __syncthreads();   // all waves' QK done -> KB free; drains vmcnt -> V(it+1) staged

    // issue K(it+1) DMA into KB (covered by PV below + other blocks)
    if (it + 1 < NT) {
      const unsigned short* ks2 = ksrc + (size_t)(it + 1) * 8192;
#pragma unroll
      for (int c = 0; c < 4; ++c) gload16(ks2 + c * 512, kdst + c * 512);
    }

    // O[n][d] += P[n][m] * V[m][d]: A = pf (regs), B = VB[it&1] chunks (mg = 4T+2s+h)
    const unsigned short* Vsh = VB + (it & 1) * 8192;
    __builtin_amdgcn_s_setprio(1);
#pragma unroll
    for (int T = 0; T < 2; ++T)
#pragma unroll
      for (int s = 0; s < 2; ++s) {
        const int mg = 4 * T + 2 * s + h;
#pragma unroll
        for (int dt = 0; dt < 4; ++dt) {
          bf16x8 bv = *reinterpret_cast<const bf16x8*>(
              &Vsh[(mg * 2 + (dt >> 1)) * 512 + ((dt & 1) * 32 + l32) * 8]);
          Oacc[dt] = __builtin_amdgcn_mfma_f32_32x32x16_bf16(pf[T][s], bv, Oacc[dt], 0, 0, 0);
        }
      }
    __builtin_amdgcn_s_setprio(0);

    __syncthreads();   // PV reads of VB[it&1] done; drains K(it+1) for next QK
  }

  // l: per-lane covers its h-half of m for q-row n=l32; merge halves
  {
    float v = lsum;
    v += __shfl_xor(v, 32);
    if (lane < 32)
      lpart[(size_t)kh * ROWS + (size_t)b * NSEQ + q0 + wv * 32 + l32] = v;
  }
  float* ob = opart + (size_t)kh * ROWS * DIM + ((size_t)b * NSEQ + q0 + wv * 32) * DIM;
  for (int dt = 0; dt < 4; ++dt)
    for (int i = 0; i < 16; ++i) {
      int n = (i & 3) + 8 * (i >> 2) + 4 * h;   // 32x32 C/D row map (measured m74/m101)
      ob[n * DIM + dt * 32 + l32] = Oacc[dt][i];
    }
}

// ---------- combine fp32 partials (4 slices), normalize, out = o @ Wp + bp ----------
// 64 rows per block (512 blocks -> 2 blocks/CU).
__global__ __launch_bounds__(256, 2) void combine_proj_kernel(
    const float* __restrict__ opart, const float* __restrict__ lpart,
    const unsigned short* __restrict__ wpT, const float* __restrict__ bp,
    float* __restrict__ out) {
  __shared__ __align__(16) unsigned short WT[128 * 136];
  const int tid = threadIdx.x;
  const int wv = tid >> 6, lane = tid & 63, l16 = lane & 15, quad = lane >> 4;
  const int row0 = blockIdx.x * 64;

  for (int p = 0; p < 8; ++p) {
    int c = p * 256 + tid;
    int col = c >> 4, c16 = c & 15;
    *reinterpret_cast<US8*>(&WT[col * 136 + c16 * 8]) =
        *reinterpret_cast<const US8*>(wpT + col * 128 + c16 * 8);
  }
  __syncthreads();

  f32x4 acc[8];
  for (int g = 0; g < 8; ++g) acc[g] = f32x4{0.f, 0.f, 0.f, 0.f};
  const int arow = row0 + wv * 16 + l16;
  float lsum = 0.f;
#pragma unroll
  for (int p = 0; p < KH; ++p) lsum += lpart[(size_t)p * ROWS + arow];
  float linv = 1.f / lsum;
  for (int s = 0; s < 4; ++s) {
    const size_t base = (size_t)arow * DIM + s * 32 + quad * 8;
    float4 s0{0.f,0.f,0.f,0.f}, s1{0.f,0.f,0.f,0.f};
#pragma unroll
    for (int p = 0; p < KH; ++p) {
      float4 u0 = *reinterpret_cast<const float4*>(opart + (size_t)p * ROWS * DIM + base);
      float4 u1 = *reinterpret_cast<const float4*>(opart + (size_t)p * ROWS * DIM + base + 4);
      s0.x += u0.x; s0.y += u0.y; s0.z += u0.z; s0.w += u0.w;
      s1.x += u1.x; s1.y += u1.y; s1.z += u1.z; s1.w += u1.w;
    }
    US8 af;
    af.us[0]=f2bf(s0.x*linv); af.us[1]=f2bf(s0.y*linv);
    af.us[2]=f2bf(s0.z*linv); af.us[3]=f2bf(s0.w*linv);
    af.us[4]=f2bf(s1.x*linv); af.us[5]=f2bf(s1.y*linv);
    af.us[6]=f2bf(s1.z*linv); af.us[7]=f2bf(s1.w*linv);
    bf16x8 a = __builtin_bit_cast(bf16x8, af);
    for (int g = 0; g < 8; ++g) {
      bf16x8 bfr = *reinterpret_cast<const bf16x8*>(&WT[(g * 16 + l16) * 136 + s * 32 + quad * 8]);
      acc[g] = __builtin_amdgcn_mfma_f32_16x16x32_bf16(a, bfr, acc[g], 0, 0, 0);
    }
  }
  for (int g = 0; g < 8; ++g) {
    float bias = bp[g * 16 + l16];
    for (int r = 0; r < 4; ++r) {
      int orow = row0 + wv * 16 + quad * 4 + r;
      out[(size_t)orow * DIM + g * 16 + l16] = acc[g][r] + bias;
    }
  }
}

extern "C" void kernel_launch(void* const* d_in, const int* in_sizes, int n_in,
                              void* d_out, int out_size, void* d_ws, size_t ws_size,
                              hipStream_t stream) {
  (void)in_sizes; (void)n_in; (void)out_size; (void)ws_size;
  const float* x   = (const float*)d_in[0];
  const float* qg  = (const float*)d_in[1];
  const float* Wkv = (const float*)d_in[2];
  const float* bkv = (const float*)d_in[3];
  const float* Wp  = (const float*)d_in[4];
  const float* bp  = (const float*)d_in[5];
  float* out = (float*)d_out;

  // workspace: 3x bf16 bufs 25.2MB | weights 96KB | l 512KB | O partials (fp32, KH=4) 67MB
  unsigned short* qbf  = (unsigned short*)d_ws;
  unsigned short* kbf  = qbf + (size_t)ROWS * DIM;
  unsigned short* vtbf = kbf + (size_t)ROWS * DIM;
  unsigned short* wkvT = vtbf + (size_t)ROWS * DIM;
  unsigned short* wpT  = wkvT + 256 * 128;
  float* lpart = (float*)(wpT + 128 * 128);
  float* opart = lpart + (size_t)KH * ROWS;

  hipLaunchKernelGGL(prep_kernel, dim3(96), dim3(256), 0, stream, Wkv, Wp, wkvT, wpT);
  hipLaunchKernelGGL(qcast_kernel, dim3(2048), dim3(256), 0, stream, qg, qbf);
  hipLaunchKernelGGL(kv_kernel, dim3(512), dim3(256), 0, stream, x, wkvT, bkv, kbf, vtbf);
  hipLaunchKernelGGL(attn_kernel, dim3(8 * 32 * KH), dim3(256), 0, stream, kbf, qbf, vtbf, opart, lpart);
  hipLaunchKernelGGL(combine_proj_kernel, dim3(ROWS / 64), dim3(256), 0, stream, opart, lpart, wpT, bp, out);
}